// Round 1
// baseline (503.704 us; speedup 1.0000x reference)
//
#include <hip/hip_runtime.h>
#include <hip/hip_fp16.h>

// Problem geometry (fixed by reference setup_inputs).
constexpr int B_ = 8;
constexpr int H_ = 480;
constexpr int W_ = 640;
constexpr int HW = H_ * W_;          // 307200
constexpr int N  = B_ * HW;          // 2457600 pixels total

__device__ __forceinline__ float to_f(float v) { return v; }
__device__ __forceinline__ float to_f(__half v) { return __half2float(v); }

// ---------------------------------------------------------------------------
// Phase 1: fused softmax + fuse-multiply weight precompute.
// w[plane][p] with plane = d_idx*9 + c, p = b*HW + i*W + j.
// w = softmax_c(guided_d[b,:,i,j])[c] * fuse[b,d,i,j]
// ---------------------------------------------------------------------------
template <typename WT>
__global__ __launch_bounds__(256) void wprep_kernel(
    const float* __restrict__ g1, const float* __restrict__ g2,
    const float* __restrict__ g3, const float* __restrict__ fuse,
    WT* __restrict__ w)
{
    const int j  = blockIdx.x * 64 + (threadIdx.x & 63);
    const int i  = blockIdx.y * 4  + (threadIdx.x >> 6);
    const int b  = blockIdx.z;
    const int hw = i * W_ + j;
    const int p  = b * HW + hw;

    const float* gs[3] = {g1, g2, g3};
#pragma unroll
    for (int d = 0; d < 3; ++d) {
        const float* gb = gs[d] + (size_t)b * 9 * HW + hw;
        float e[9];
        float m = -1e30f;
#pragma unroll
        for (int c = 0; c < 9; ++c) {
            e[c] = gb[(size_t)c * HW];
            m = fmaxf(m, e[c]);
        }
        float s = 0.f;
#pragma unroll
        for (int c = 0; c < 9; ++c) {
            e[c] = __expf(e[c] - m);
            s += e[c];
        }
        const float f = fuse[((size_t)b * 3 + d) * HW + hw] / s;
#pragma unroll
        for (int c = 0; c < 9; ++c) {
            w[(size_t)(d * 9 + c) * N + p] = (WT)(e[c] * f);
        }
    }
}

// ---------------------------------------------------------------------------
// Phase 2: one propagation step. out[p] = sum over 27 taps of x * w.
// Tap (d, ki, kj): offset ((ki-1)*d, (kj-1)*d), zero outside the image.
// ---------------------------------------------------------------------------
template <typename WT>
__global__ __launch_bounds__(256) void prop_kernel(
    const float* __restrict__ xin, const WT* __restrict__ w,
    float* __restrict__ xout)
{
    const int j  = blockIdx.x * 64 + (threadIdx.x & 63);
    const int i  = blockIdx.y * 4  + (threadIdx.x >> 6);
    const int b  = blockIdx.z;
    const int hw = i * W_ + j;
    const int p  = b * HW + hw;

    const float* xb = xin + (size_t)b * HW;
    float acc = 0.f;
#pragma unroll
    for (int d = 1; d <= 3; ++d) {
#pragma unroll
        for (int ki = 0; ki < 3; ++ki) {
            const int ii = i + (ki - 1) * d;
#pragma unroll
            for (int kj = 0; kj < 3; ++kj) {
                const int jj = j + (kj - 1) * d;
                float xv = 0.f;
                if (ii >= 0 && ii < H_ && jj >= 0 && jj < W_)
                    xv = xb[ii * W_ + jj];
                const int plane = (d - 1) * 9 + ki * 3 + kj;
                acc = fmaf(xv, to_f(w[(size_t)plane * N + p]), acc);
            }
        }
    }
    xout[p] = acc;
}

// ---------------------------------------------------------------------------
extern "C" void kernel_launch(void* const* d_in, const int* in_sizes, int n_in,
                              void* d_out, int out_size, void* d_ws, size_t ws_size,
                              hipStream_t stream)
{
    const float* g1   = (const float*)d_in[0];
    const float* g2   = (const float*)d_in[1];
    const float* g3   = (const float*)d_in[2];
    const float* fuse = (const float*)d_in[3];
    const float* x    = (const float*)d_in[4];
    float* out = (float*)d_out;

    const dim3 grid(W_ / 64, H_ / 4, B_);
    const dim3 block(256);

    char* ws = (char*)d_ws;
    const size_t need_f32 = (size_t)27 * N * 4 + (size_t)2 * N * 4;

    if (ws_size >= need_f32) {
        // fp32 weight path (accuracy-safe).
        float* w  = (float*)ws;
        float* xa = (float*)(ws + (size_t)27 * N * 4);
        float* xb = xa + N;
        wprep_kernel<float><<<grid, block, 0, stream>>>(g1, g2, g3, fuse, w);
        float* bufs[2] = {xa, xb};
        const float* src = x;
        for (int t = 0; t < 8; ++t) {
            float* dst = (t == 7) ? out : bufs[t & 1];
            prop_kernel<float><<<grid, block, 0, stream>>>(src, w, dst);
            src = dst;
        }
    } else {
        // fp16 weight fallback (smaller ws): 27*N*2 + 2*N*4 bytes.
        __half* w = (__half*)ws;
        float* xa = (float*)(ws + (size_t)27 * N * 2);
        float* xb = xa + N;
        wprep_kernel<__half><<<grid, block, 0, stream>>>(g1, g2, g3, fuse, w);
        float* bufs[2] = {xa, xb};
        const float* src = x;
        for (int t = 0; t < 8; ++t) {
            float* dst = (t == 7) ? out : bufs[t & 1];
            prop_kernel<__half><<<grid, block, 0, stream>>>(src, w, dst);
            src = dst;
        }
    }
}